// Round 1
// 200.579 us; speedup vs baseline: 1.0223x; 1.0223x over previous
//
#include <hip/hip_runtime.h>
#include <hip/hip_bf16.h>

// CTC loss, FUSED single kernel: one block per batch element, 512 thr = 8 waves.
// R1 (this session): producer-consumer overlap — NO barrier between gather and
//   scan. Every wave gathers 8 chunks (wave 0 takes the LAST 8, produced first;
//   waves 1-7 take chunks (w-1)+7k so ready-order ~= scan order). Per-chunk
//   LDS ready[] flags: producer drains lgkmcnt then sets flag; wave 0's scan
//   polls (acquire + s_sleep) only for chunks < 56. The serial f64 scan now
//   hides under the HBM-bound gather instead of running as a tail after it.
//   Phase A (all 8 waves): gather p[b][t][ext_r]+EPS -> bf16, packed 8 steps
//     per uint4, into LDS sG[chunk][r] (r<64: label rows, r==64: blank).
//     NONTEMPORAL coalesced u64 row loads (y_pred read exactly once; harness
//     leaves L3 full of dirty poison lines -> allocating reads pay a ~1:1
//     writeback tax; nt loads dodge it) + ds_bpermute lane crossbar.
//   Phase B (wave 0, chasing the producers): alpha recursion in LINEAR f64
//     domain, DPP wave_shr neighbor term, exact power-of-2 renorm every 32
//     steps via integer exponent max-reduce. 4-slot LDS prefetch.
// R7 lesson (prev session): NO min-waves clause (VGPR cap 64 spilled phase-B
// banks: 203 MB scratch traffic). Occupancy is LDS-capped at 2 blocks/CU.

typedef unsigned int u32;
typedef unsigned long long u64;

constexpr int B = 512, T = 512, C = 128, L = 64;
constexpr int NCHUNK = T / 8;    // 64 chunks of 8 timesteps
constexpr int W0_FIRST = 56;     // chunks 56..63: produced by wave 0 itself
constexpr float EPS = 1e-7f;
constexpr float LN2 = 0.69314718055994530942f;

__device__ __forceinline__ u32 rne16(u32 b) {       // f32 bits -> bf16 (RNE)
    return (b + 0x7FFFu + ((b >> 16) & 1u)) >> 16;
}
__device__ __forceinline__ double dpp64_shr1(double x) {
    // lane i <- lane i-1 ; lane 0 -> 0.0
    union { double d; u32 u[2]; } in, out;
    in.d = x;
    out.u[0] = (u32)__builtin_amdgcn_update_dpp(0, (int)in.u[0], 0x138, 0xF, 0xF, false);
    out.u[1] = (u32)__builtin_amdgcn_update_dpp(0, (int)in.u[1], 0x138, 0xF, 0xF, false);
    return out.d;
}
template <int CTRL>
__device__ __forceinline__ u32 dpp_maxu_step(u32 m) {
    u32 t = (u32)__builtin_amdgcn_update_dpp(0, (int)m, CTRL, 0xF, 0xF, false);
    return m > t ? m : t;
}
__device__ __forceinline__ double exp2_exact(int e) {  // 2^e
    union { double d; u64 u; } s; s.u = (u64)(1023 + e) << 52; return s.d;
}
__device__ __forceinline__ void wait_ready(int* f) {
    while (__hip_atomic_load(f, __ATOMIC_ACQUIRE, __HIP_MEMORY_SCOPE_WORKGROUP) == 0)
        __builtin_amdgcn_s_sleep(1);
}

__global__ __launch_bounds__(512)
void ctc_fused(const int* __restrict__ y_true,
               const float* __restrict__ y_pred,
               float* __restrict__ out) {
    __shared__ uint4 sG[NCHUNK * 65];   // 66560 B: [chunk][r], r=64 is blank
    __shared__ int   ready[NCHUNK];     // per-chunk producer->consumer flag

    const int b    = blockIdx.x;
    const int wave = threadIdx.x >> 6;
    const int lane = threadIdx.x & 63;

    const int lab  = y_true[b * L + lane];   // label of row r=lane
    const int perm = (lab >> 1) << 2;        // bpermute byte address
    const bool sel_hi = (lab & 1);

    if (threadIdx.x < NCHUNK) ready[threadIdx.x] = 0;
    __syncthreads();   // flags zeroed before any producer can set them;
                       // the ONLY barrier — all 512 threads reach it.

    // ---------------- produce: every wave gathers 8 chunks ----------------
    {
        // lane owns classes 2*lane, 2*lane+1 of each t-row (u64 = 2 floats)
        const u64* __restrict__ base =
            (const u64*)(y_pred + (size_t)b * T * C) + lane;
        const int start  = (wave == 0) ? W0_FIRST : (wave - 1);
        const int stride = (wave == 0) ? 1 : 7;

        u64 buf[2][8];
#pragma unroll
        for (int j = 0; j < 8; ++j)
            buf[0][j] = __builtin_nontemporal_load(base + (start * 8 + j) * 64);

#pragma unroll
        for (int k = 0; k < 8; ++k) {
            const int c = start + stride * k;
            if (k + 1 < 8) {
                const int cn = c + stride;
#pragma unroll
                for (int j = 0; j < 8; ++j)
                    buf[(k + 1) & 1][j] =
                        __builtin_nontemporal_load(base + (cn * 8 + j) * 64);
            }
            const u64* row = buf[k & 1];

            u32 gl[8], gb[8];
#pragma unroll
            for (int j = 0; j < 8; ++j) {
                const int lo = (int)(u32)row[j];
                const int hi = (int)(u32)(row[j] >> 32);
                const int vx = __builtin_amdgcn_ds_bpermute(perm, lo);
                const int vy = __builtin_amdgcn_ds_bpermute(perm, hi);
                gl[j] = __float_as_uint(__int_as_float(sel_hi ? vy : vx) + EPS);
                // class 127 = hi dword of lane 63 (wave-uniform broadcast)
                gb[j] = __float_as_uint(
                    __int_as_float(__builtin_amdgcn_readlane(hi, 63)) + EPS);
            }
            u32 wl[4], wb[4];
#pragma unroll
            for (int q = 0; q < 4; ++q) {
                wl[q] = rne16(gl[2 * q]) | (rne16(gl[2 * q + 1]) << 16);
                wb[q] = rne16(gb[2 * q]) | (rne16(gb[2 * q + 1]) << 16);
            }
            sG[c * 65 + lane] = make_uint4(wl[0], wl[1], wl[2], wl[3]);
            if (lane == 0)
                sG[c * 65 + 64] = make_uint4(wb[0], wb[1], wb[2], wb[3]);

            // Publish: drain this wave's ds_writes, then set the flag.
            asm volatile("s_waitcnt lgkmcnt(0)" ::: "memory");
            if (lane == 0)
                __hip_atomic_store(&ready[c], 1, __ATOMIC_RELAXED,
                                   __HIP_MEMORY_SCOPE_WORKGROUP);
        }
    }
    if (wave != 0) return;           // waves 1-7 done

    // ---------------- scan: wave 0 chases the producers ----------------
    const int lab_prev = __shfl_up(lab, 1);
    const bool allow1 = (lane >= 1) && (lab != lab_prev);

    // 4-slot rotating LDS prefetch (distance 4 chunks).
    uint4 so[4], sb[4];
#pragma unroll
    for (int c = 0; c < 4; ++c) {
        wait_ready(&ready[c]);
        so[c] = sG[c * 65 + lane];
        sb[c] = sG[c * 65 + 64];
    }

    // Virtual pre-state: step t=0 of the uniform body produces the true init.
    double d0 = (lane == 0) ? 1.0 : 0.0;   // alpha[2l]
    double d1 = 0.0;                       // alpha[2l+1]
    double d2 = 0.0;                       // alpha[128] (real on lane 63)
    int Ce = 0;                            // log2 scale: alpha_true = d * 2^Ce

#pragma unroll 4
    for (int c = 0; c < NCHUNK; ++c) {
        const int slot = c & 3;
        const uint4 uo = so[slot];
        const uint4 ub = sb[slot];
        const int nc = c + 4;
        if (nc < NCHUNK) {                  // wave-uniform
            if (nc < W0_FIRST) wait_ready(&ready[nc]);  // own chunks need no flag
            so[slot] = sG[nc * 65 + lane];
            sb[slot] = sG[nc * 65 + 64];
        }

        const u32* ow = (const u32*)&uo;
        const u32* bw = (const u32*)&ub;
#pragma unroll
        for (int j = 0; j < 8; ++j) {
            const u32 wo = ow[j >> 1], wb = bw[j >> 1];
            const float fl = __uint_as_float((j & 1) ? (wo & 0xFFFF0000u) : (wo << 16));
            const float fb = __uint_as_float((j & 1) ? (wb & 0xFFFF0000u) : (wb << 16));
            const double Pl = (double)fl, Pb = (double)fb;
            const double p0  = dpp64_shr1(d1);     // alpha[2l-1]
            const double s01 = d0 + d1;            // independent of p0
            const double sel = allow1 ? p0 : 0.0;
            const double nd0 = (d0 + p0) * Pb;
            const double nd2 = (d2 + d1) * Pb;
            const double nd1 = (s01 + sel) * Pl;
            d0 = nd0; d1 = nd1; d2 = nd2;
        }

        if ((c & 3) == 3) {                 // renorm every 32 steps
            u32 h0 = (u32)__double2hiint(d0);
            u32 h1 = (u32)__double2hiint(d1);
            u32 m = h0 > h1 ? h0 : h1;
            m = dpp_maxu_step<0x111>(m);     // row_shr:1
            m = dpp_maxu_step<0x112>(m);     // row_shr:2
            m = dpp_maxu_step<0x114>(m);     // row_shr:4
            m = dpp_maxu_step<0x118>(m);     // row_shr:8
            m = dpp_maxu_step<0x142>(m);     // row_bcast:15
            m = dpp_maxu_step<0x143>(m);     // row_bcast:31 -> lane 63 has max
            const u32 M = (u32)__builtin_amdgcn_readlane((int)m, 63);
            const int e = (int)((M >> 20) & 0x7FFu) - 1023;
            const double s = exp2_exact(-e);
            d0 *= s; d1 *= s; d2 *= s;
            Ce += e;
        }
    }

    if (lane == 63) {
        const double sum = d1 + d2;                   // alpha[127]+alpha[128]
        const int ee = ((__double2hiint(sum) >> 20) & 0x7FF) - 1023;
        const float mant = (float)(sum * exp2_exact(-ee));   // in [1,2)
        out[b] = -((float)(Ce + ee) + __log2f(mant)) * LN2;
    }
}

extern "C" void kernel_launch(void* const* d_in, const int* in_sizes, int n_in,
                              void* d_out, int out_size, void* d_ws, size_t ws_size,
                              hipStream_t stream) {
    const int*   y_true = (const int*)d_in[0];
    const float* y_pred = (const float*)d_in[1];
    float*       out    = (float*)d_out;
    ctc_fused<<<dim3(B), dim3(512), 0, stream>>>(y_true, y_pred, out);
}